// Round 4
// baseline (214.048 us; speedup 1.0000x reference)
//
#include <hip/hip_runtime.h>

#define WAVES_PER_BLOCK 4
#define N_VERT 16384

__global__ __launch_bounds__(256) void vertex_mlp_kernel(
    const float* __restrict__ vf,   // (N,16,128)
    const float* __restrict__ py,   // (N,128,2)
    const float* __restrict__ vp,   // (N,233,1)
    float* __restrict__ out)        // (N,128)
{
    const int wave = threadIdx.x >> 6;
    const int lane = threadIdx.x & 63;
    const int n = blockIdx.x * WAVES_PER_BLOCK + wave;

    __shared__ float sp[WAVES_PER_BLOCK][240];  // 240: pad to keep wave rows apart

    // ---- issue ALL independent global loads first (latency overlap) ----

    // params: 233 floats, 4 coalesced rounds of 64 lanes
    const float* __restrict__ p = vp + (size_t)n * 233;
    float pr0 = p[lane];
    float pr1 = p[lane + 64];
    float pr2 = p[lane + 128];
    float pr3 = (lane < 233 - 192) ? p[lane + 192] : 0.0f;

    // py_pred: lane owns columns 2*lane, 2*lane+1; (P,2) interleaved layout
    // one float4 = {py[2l][0], py[2l][1], py[2l+1][0], py[2l+1][1]}
    const float4 pyv = *(const float4*)(py + (size_t)n * 256 + lane * 4);

    // features: 16 rows, float2 per lane (columns 2l, 2l+1), 512B/wave/instr
    float2 xv[16];
    const float* __restrict__ vfn = vf + (size_t)n * 16 * 128;
    #pragma unroll
    for (int i = 0; i < 16; i++) {
        xv[i] = *(const float2*)(vfn + i * 128 + lane * 2);
    }

    // ---- stage params into this wave's LDS slice ----
    sp[wave][lane]       = pr0;
    sp[wave][lane + 64]  = pr1;
    sp[wave][lane + 128] = pr2;
    if (lane < 233 - 192) sp[wave][lane + 192] = pr3;

    // ---- per-channel min over the 128 columns (wave butterfly) ----
    float m0 = fminf(pyv.x, pyv.z);
    float m1 = fminf(pyv.y, pyv.w);
    #pragma unroll
    for (int off = 1; off < 64; off <<= 1) {
        m0 = fminf(m0, __shfl_xor(m0, off));
        m1 = fminf(m1, __shfl_xor(m1, off));
    }
    // (py/RO - min(py/RO))*RO == py - min(py) exactly in fp32 (RO=4 is a power of 2)
    const float x16a = pyv.x - m0, x17a = pyv.y - m1;  // column 2*lane
    const float x16b = pyv.z - m0, x17b = pyv.w - m1;  // column 2*lane+1

    __syncthreads();  // params staged (one barrier; waves arrive together)

    const float* __restrict__ W = sp[wave];

    // ---- layer 0: 18 -> 8 + ReLU.  W0[j][i] = W[j*18+i], b0 = W[144+j] ----
    float h0a[8], h0b[8];
    #pragma unroll
    for (int j = 0; j < 8; j++) {
        float a = W[144 + j];
        float b = a;
        #pragma unroll
        for (int i = 0; i < 16; i++) {
            const float w = W[j * 18 + i];
            a = fmaf(w, xv[i].x, a);
            b = fmaf(w, xv[i].y, b);
        }
        const float w16 = W[j * 18 + 16], w17 = W[j * 18 + 17];
        a = fmaf(w16, x16a, fmaf(w17, x17a, a));
        b = fmaf(w16, x16b, fmaf(w17, x17b, b));
        h0a[j] = fmaxf(a, 0.0f);
        h0b[j] = fmaxf(b, 0.0f);
    }

    // ---- layer 1: 8 -> 8 + ReLU.  W1[j][i] = W[152+j*8+i], b1 = W[216+j] ----
    float h1a[8], h1b[8];
    #pragma unroll
    for (int j = 0; j < 8; j++) {
        float a = W[216 + j];
        float b = a;
        #pragma unroll
        for (int i = 0; i < 8; i++) {
            const float w = W[152 + j * 8 + i];
            a = fmaf(w, h0a[i], a);
            b = fmaf(w, h0b[i], b);
        }
        h1a[j] = fmaxf(a, 0.0f);
        h1b[j] = fmaxf(b, 0.0f);
    }

    // ---- layer 2: 8 -> 1.  W2[i] = W[224+i], b2 = W[232] ----
    float oa = W[232], ob = W[232];
    #pragma unroll
    for (int i = 0; i < 8; i++) {
        const float w = W[224 + i];
        oa = fmaf(w, h1a[i], oa);
        ob = fmaf(w, h1b[i], ob);
    }

    *(float2*)(out + (size_t)n * 128 + lane * 2) = make_float2(oa, ob);
}

extern "C" void kernel_launch(void* const* d_in, const int* in_sizes, int n_in,
                              void* d_out, int out_size, void* d_ws, size_t ws_size,
                              hipStream_t stream) {
    const float* vf = (const float*)d_in[0];   // vertex_feature (N,16,128)
    const float* py = (const float*)d_in[1];   // py_pred        (N,128,2)
    const float* vp = (const float*)d_in[2];   // vertex_params  (N,233,1)
    float* out = (float*)d_out;                // (N,128)

    const int grid = N_VERT / WAVES_PER_BLOCK; // 4096 blocks x 4 waves = 16384 vertices
    vertex_mlp_kernel<<<grid, 256, 0, stream>>>(vf, py, vp, out);
}